// Round 4
// baseline (135.886 us; speedup 1.0000x reference)
//
#include <hip/hip_runtime.h>

// Problem constants (from reference)
constexpr int   NB         = 128;          // bins per axis
constexpr int   NCELL      = NB * NB;      // 16384 cells
constexpr int   NFL        = 2 * NCELL;    // [Dx | Dy] floats = 32768 (de-interleaved)
constexpr float S          = 7.8125f;      // 1000/128, exact in fp32
constexpr int   NUM_NETS   = 100000;
constexpr int   NUM_NODES  = 200000;
constexpr int   NUM_MOVABLE= 180000;
constexpr int   NUM_PINS   = 400000;
constexpr float UNIT_H_CAP = 1.5f;
constexpr float UNIT_V_CAP = 1.4f;

#define TPB    1024  // scatter block size
#define NDB    128   // scatter blocks (128 KB LDS each, 1/CU). P = 16.8 MB.
#define NCHUNK 8     // reduce b-parallelism

__device__ __forceinline__ float edgef(int t) { return (float)t * S; }

__device__ __forceinline__ int bin_of(float v) {
    int t = (int)floorf(v / S);
    while (edgef(t + 1) <= v) ++t;
    while (edgef(t)     >  v) --t;
    return t;
}

__device__ __forceinline__ float phi(int t, float lo, float hi) {
    return fminf(fmaxf(edgef(t), lo), hi);
}

// second difference of the clamp-ramp: <=4 nonzeros (indices >=128 dropped by
// caller; they never influence bins 0..127).
__device__ __forceinline__ int second_diff(float lo, float hi,
                                           int* idx, float* val) {
    int a = bin_of(lo);
    int b = bin_of(hi);
    int n = 0;
    idx[n] = a;
    val[n] = phi(a + 1, lo, hi) - 2.f * phi(a, lo, hi) + phi(a - 1, lo, hi);
    ++n;
    idx[n] = a + 1;
    val[n] = phi(a + 2, lo, hi) - 2.f * phi(a + 1, lo, hi) + phi(a, lo, hi);
    ++n;
    if (b > a + 1) {
        idx[n] = b;
        val[n] = phi(b + 1, lo, hi) - 2.f * phi(b, lo, hi) + phi(b - 1, lo, hi);
        ++n;
    }
    if (b > a) {
        idx[n] = b + 1;
        val[n] = phi(b + 2, lo, hi) - 2.f * phi(b + 1, lo, hi) + phi(b, lo, hi);
        ++n;
    }
    return n;
}

// K1a: pure bbox gather. One net per thread, NO LDS -> occupancy limited only
// by VGPRs (20): all 256 CUs, many waves/CU, maximal MLP for the 800K random
// 4B pin_pos loads. Emits compact coalesced per-net records.
__global__ __launch_bounds__(256) void bbox_kernel(
    const float* __restrict__ pin_pos,
    const float* __restrict__ net_weights,
    const int*   __restrict__ nps,
    const int*   __restrict__ fnp,
    float4* __restrict__ bbox,      // [NUM_NETS] (xmin,xmax,ymin,ymax)
    float2* __restrict__ cxy) {     // [NUM_NETS] (cx,cy)
    int n = blockIdx.x * 256 + threadIdx.x;
    if (n >= NUM_NETS) return;
    int s = nps[n], e = nps[n + 1];
    if (e <= s) {
        bbox[n] = make_float4(0.f, 0.f, 0.f, 0.f);
        cxy[n]  = make_float2(0.f, 0.f);
        return;
    }
    float xmin, xmax, ymin, ymax;
    if (e - s == 4 && (s & 3) == 0) {
        int4 p4 = *(const int4*)(fnp + s);
        float x0 = pin_pos[p4.x], y0 = pin_pos[p4.x + NUM_PINS];
        float x1 = pin_pos[p4.y], y1 = pin_pos[p4.y + NUM_PINS];
        float x2 = pin_pos[p4.z], y2 = pin_pos[p4.z + NUM_PINS];
        float x3 = pin_pos[p4.w], y3 = pin_pos[p4.w + NUM_PINS];
        xmin = fminf(fminf(x0, x1), fminf(x2, x3));
        xmax = fmaxf(fmaxf(x0, x1), fmaxf(x2, x3));
        ymin = fminf(fminf(y0, y1), fminf(y2, y3));
        ymax = fmaxf(fmaxf(y0, y1), fmaxf(y2, y3));
    } else {
        xmin = 1e30f; xmax = -1e30f; ymin = 1e30f; ymax = -1e30f;
        for (int p = s; p < e; ++p) {
            int pin = fnp[p];
            float px = pin_pos[pin];
            float py = pin_pos[pin + NUM_PINS];
            xmin = fminf(xmin, px); xmax = fmaxf(xmax, px);
            ymin = fminf(ymin, py); ymax = fmaxf(ymax, py);
        }
    }
    float w  = net_weights[n];
    float dx = xmax - xmin, dy = ymax - ymin;
    float cx = (dy > 0.f) ? w / dy : 0.f;   // map_x coeff
    float cy = (dx > 0.f) ? w / dx : 0.f;   // map_y coeff
    bbox[n] = make_float4(xmin, xmax, ymin, ymax);
    cxy[n]  = make_float2(cx, cy);
}

// K1b: LDS-private scatter from coalesced per-net records into DE-INTERLEAVED
// Dx/Dy halves (128 KB dynamic LDS), then bulk float4 writeback to P[b].
// Contiguous net range per block; all input reads are perfectly coalesced.
__global__ __launch_bounds__(TPB) void scatter_kernel(
    const float4* __restrict__ bbox,
    const float2* __restrict__ cxy,
    float* __restrict__ P) {            // [B][NFL]
    extern __shared__ float Dl[];       // [Dx NCELL | Dy NCELL]
    const int tid = threadIdx.x;

    float4* D4 = (float4*)Dl;
    for (int i = tid; i < NFL / 4; i += TPB) D4[i] = make_float4(0, 0, 0, 0);
    __syncthreads();

    const int per = (NUM_NETS + gridDim.x - 1) / gridDim.x;
    const int n0  = blockIdx.x * per;
    const int n1  = min(n0 + per, NUM_NETS);

    for (int n = n0 + tid; n < n1; n += TPB) {
        float2 c = cxy[n];
        float cx = c.x, cy = c.y;
        if (cx == 0.f && cy == 0.f) continue;
        float4 bb = bbox[n];

        int ixs[4], iys[4];
        float vxs[4], vys[4];
        int nx = second_diff(bb.x, bb.y, ixs, vxs);
        int ny = second_diff(bb.z, bb.w, iys, vys);

        for (int i = 0; i < nx; ++i) {
            int row = ixs[i];
            float fi = vxs[i];
            if (fi == 0.f || row >= NB) continue;
            for (int j = 0; j < ny; ++j) {
                int col = iys[j];
                float t = fi * vys[j];
                if (t == 0.f || col >= NB) continue;
                int cell = row * NB + col;
                if (cx != 0.f) atomicAdd(&Dl[cell],         cx * t);
                if (cy != 0.f) atomicAdd(&Dl[NCELL + cell], cy * t);
            }
        }
    }
    __syncthreads();

    float4* Pb = (float4*)(P + (size_t)blockIdx.x * NFL);
    for (int i = tid; i < NFL / 4; i += TPB) Pb[i] = D4[i];
}

// K2: chunked reduce: Rc[chunk][NFL] = sum of partial slice. Coalesced float4.
__global__ __launch_bounds__(256) void reduce_kernel(
    const float4* __restrict__ P,   // [B][NFL/4]
    float4* __restrict__ Rc,        // [NCHUNK][NFL/4]
    int B) {
    constexpr int NF4 = NFL / 4;    // 8192
    int g = blockIdx.x * blockDim.x + threadIdx.x;   // 0..8191
    int chunk = blockIdx.y;
    int per = (B + NCHUNK - 1) / NCHUNK;
    int b0 = chunk * per;
    int b1 = min(b0 + per, B);
    float4 a0 = {0,0,0,0}, a1 = {0,0,0,0}, a2 = {0,0,0,0}, a3 = {0,0,0,0};
    int b = b0;
    for (; b + 3 < b1; b += 4) {
        float4 v0 = P[(size_t)(b    ) * NF4 + g];
        float4 v1 = P[(size_t)(b + 1) * NF4 + g];
        float4 v2 = P[(size_t)(b + 2) * NF4 + g];
        float4 v3 = P[(size_t)(b + 3) * NF4 + g];
        a0.x += v0.x; a0.y += v0.y; a0.z += v0.z; a0.w += v0.w;
        a1.x += v1.x; a1.y += v1.y; a1.z += v1.z; a1.w += v1.w;
        a2.x += v2.x; a2.y += v2.y; a2.z += v2.z; a2.w += v2.w;
        a3.x += v3.x; a3.y += v3.y; a3.z += v3.z; a3.w += v3.w;
    }
    for (; b < b1; ++b) {
        float4 v = P[(size_t)b * NF4 + g];
        a0.x += v.x; a0.y += v.y; a0.z += v.z; a0.w += v.w;
    }
    float4 r;
    r.x = (a0.x + a1.x) + (a2.x + a3.x);
    r.y = (a0.y + a1.y) + (a2.y + a3.y);
    r.z = (a0.z + a1.z) + (a2.z + a3.z);
    r.w = (a0.w + a1.w) + (a2.w + a3.w);
    Rc[(size_t)chunk * NF4 + g] = r;
}

// K3: x-prefix. One block per y-column; thread t = x-row. Sums the 8 chunk
// maps for both (de-interleaved) halves, LDS Hillis-Steele scan over 128 rows.
__global__ __launch_bounds__(NB) void scan_x_kernel(
    const float* __restrict__ Rc,    // [NCHUNK][2][NCELL]
    float2* __restrict__ Xp) {       // [NCELL] float2, x-prefixed
    __shared__ float2 sm[NB];
    int col = blockIdx.x;
    int t = threadIdx.x;
    int idx = t * NB + col;
    float2 v = make_float2(0.f, 0.f);
    #pragma unroll
    for (int c = 0; c < NCHUNK; ++c) {
        v.x += Rc[(size_t)c * NFL + idx];
        v.y += Rc[(size_t)c * NFL + NCELL + idx];
    }
    sm[t] = v;
    __syncthreads();
    #pragma unroll
    for (int off = 1; off < NB; off <<= 1) {
        float2 cur = sm[t];
        float2 add = (t >= off) ? sm[t - off] : make_float2(0.f, 0.f);
        __syncthreads();
        cur.x += add.x; cur.y += add.y;
        sm[t] = cur;
        __syncthreads();
    }
    Xp[idx] = sm[t];
}

// K4: y-prefix + clip -> util. One block per x-row; coalesced float2 loads.
__global__ __launch_bounds__(NB) void scan_y_kernel(
    const float2* __restrict__ Xp,   // [NCELL] float2
    float* __restrict__ util) {
    __shared__ float2 sm[NB];
    int row = blockIdx.x;
    int t = threadIdx.x;
    sm[t] = Xp[row * NB + t];
    __syncthreads();
    #pragma unroll
    for (int off = 1; off < NB; off <<= 1) {
        float2 cur = sm[t];
        float2 add = (t >= off) ? sm[t - off] : make_float2(0.f, 0.f);
        __syncthreads();
        cur.x += add.x; cur.y += add.y;
        sm[t] = cur;
        __syncthreads();
    }
    constexpr float invx = 1.f / (S * S * UNIT_H_CAP);
    constexpr float invy = 1.f / (S * S * UNIT_V_CAP);
    float2 r = sm[t];
    float u = fmaxf(r.x * invx, r.y * invy);
    util[row * NB + t] = fminf(fmaxf(u, 0.5f), 2.0f);
}

// K5: per-movable-node area = sum over <=3x3 bins of ox*util*oy
__global__ __launch_bounds__(256) void node_kernel(
    const float* __restrict__ pos,
    const float* __restrict__ nsx,
    const float* __restrict__ nsy,
    const float* __restrict__ util,
    float* __restrict__ out) {
    int m = blockIdx.x * blockDim.x + threadIdx.x;
    if (m >= NUM_MOVABLE) return;
    float x  = pos[m];
    float y  = pos[NUM_NODES + m];
    float xh = x + nsx[m];
    float yh = y + nsy[m];
    int ax = max(0,      (int)floorf(x  / S) - 1);
    int bx = min(NB - 1, (int)floorf(xh / S) + 1);
    int ay = max(0,      (int)floorf(y  / S) - 1);
    int by = min(NB - 1, (int)floorf(yh / S) + 1);
    float acc = 0.f;
    for (int i = ax; i <= bx; ++i) {
        float ov = fminf(edgef(i + 1), xh) - fmaxf(edgef(i), x);
        if (ov <= 0.f) continue;
        float inner = 0.f;
        for (int j = ay; j <= by; ++j) {
            float ovy = fminf(edgef(j + 1), yh) - fmaxf(edgef(j), y);
            if (ovy > 0.f) inner += ovy * util[i * NB + j];
        }
        acc += ov * inner;
    }
    out[m] = acc;
}

extern "C" void kernel_launch(void* const* d_in, const int* in_sizes, int n_in,
                              void* d_out, int out_size, void* d_ws, size_t ws_size,
                              hipStream_t stream) {
    const float* pos      = (const float*)d_in[0];
    const float* pin_pos  = (const float*)d_in[1];
    const float* nsx      = (const float*)d_in[2];
    const float* nsy      = (const float*)d_in[3];
    const float* nw       = (const float*)d_in[4];
    const int*   npstart  = (const int*)d_in[5];
    const int*   fnp      = (const int*)d_in[6];
    float*       out      = (float*)d_out;

    // ws layout (floats):
    //   Rc[NCHUNK*NFL] | Xp[NFL] | util[NCELL] | bbox[4*NUM_NETS] |
    //   cxy[2*NUM_NETS] | P[B*NFL]
    float* w    = (float*)d_ws;
    float* Rc   = w;                           w += NCHUNK * NFL;
    float* Xp   = w;                           w += NFL;
    float* util = w;                           w += NCELL;
    float* bbox = w;                           w += 4 * NUM_NETS;
    float* cxy  = w;                           w += 2 * NUM_NETS;
    float* P    = w;

    size_t fixed = (size_t)(w - (float*)d_ws) * sizeof(float);
    int B = NDB;
    if (ws_size > fixed) {
        size_t fit = (ws_size - fixed) / ((size_t)NFL * sizeof(float));
        if ((size_t)B > fit) B = (int)fit;
    } else {
        B = 1;
    }
    if (B < 1) B = 1;

    (void)hipFuncSetAttribute((const void*)scatter_kernel,
                              hipFuncAttributeMaxDynamicSharedMemorySize,
                              NFL * (int)sizeof(float));

    bbox_kernel<<<(NUM_NETS + 255) / 256, 256, 0, stream>>>(
        pin_pos, nw, npstart, fnp, (float4*)bbox, (float2*)cxy);
    scatter_kernel<<<B, TPB, NFL * sizeof(float), stream>>>(
        (const float4*)bbox, (const float2*)cxy, P);
    {
        dim3 g(NFL / 4 / 256, NCHUNK);   // 32 x 8 blocks
        reduce_kernel<<<g, 256, 0, stream>>>(
            (const float4*)P, (float4*)Rc, B);
    }
    scan_x_kernel<<<NB, NB, 0, stream>>>(Rc, (float2*)Xp);
    scan_y_kernel<<<NB, NB, 0, stream>>>((const float2*)Xp, util);
    node_kernel<<<(NUM_MOVABLE + 255) / 256, 256, 0, stream>>>(
        pos, nsx, nsy, util, out);
}

// Round 5
// 116.184 us; speedup vs baseline: 1.1696x; 1.1696x over previous
//
#include <hip/hip_runtime.h>

// Problem constants (from reference)
constexpr int   NB         = 128;          // bins per axis
constexpr int   NCELL      = NB * NB;      // 16384 cells
constexpr int   NFL        = 2 * NCELL;    // [Dx | Dy] floats = 32768 (de-interleaved)
constexpr float S          = 7.8125f;      // 1000/128, exact in fp32
constexpr int   NUM_NETS   = 100000;
constexpr int   NUM_NODES  = 200000;
constexpr int   NUM_MOVABLE= 180000;
constexpr int   NUM_PINS   = 400000;
constexpr float UNIT_H_CAP = 1.5f;
constexpr float UNIT_V_CAP = 1.4f;

#define TPB    1024  // net_diff block size (16 waves: fast init/writeback)
#define NDB    256   // net_diff blocks: 1 per CU on ALL 256 CUs.
                     // LDS-atomic pipe is per-CU -> this halves the per-CU
                     // atomic load vs 128 blocks (the round-3 45.5us culprit).
#define NCHUNK 8     // reduce chunks == XCD count (XCD-affine slice sums)

__device__ __forceinline__ float edgef(int t) { return (float)t * S; }

__device__ __forceinline__ int bin_of(float v) {
    int t = (int)floorf(v / S);
    while (edgef(t + 1) <= v) ++t;
    while (edgef(t)     >  v) --t;
    return t;
}

__device__ __forceinline__ float phi(int t, float lo, float hi) {
    return fminf(fmaxf(edgef(t), lo), hi);
}

// second difference of the clamp-ramp: <=4 nonzeros (indices >=128 dropped by
// caller; they never influence bins 0..127).
__device__ __forceinline__ int second_diff(float lo, float hi,
                                           int* idx, float* val) {
    int a = bin_of(lo);
    int b = bin_of(hi);
    int n = 0;
    idx[n] = a;
    val[n] = phi(a + 1, lo, hi) - 2.f * phi(a, lo, hi) + phi(a - 1, lo, hi);
    ++n;
    idx[n] = a + 1;
    val[n] = phi(a + 2, lo, hi) - 2.f * phi(a + 1, lo, hi) + phi(a, lo, hi);
    ++n;
    if (b > a + 1) {
        idx[n] = b;
        val[n] = phi(b + 1, lo, hi) - 2.f * phi(b, lo, hi) + phi(b - 1, lo, hi);
        ++n;
    }
    if (b > a) {
        idx[n] = b + 1;
        val[n] = phi(b + 2, lo, hi) - 2.f * phi(b + 1, lo, hi) + phi(b, lo, hi);
        ++n;
    }
    return n;
}

// K1: fused bbox gather + LDS-private scatter into DE-INTERLEAVED Dx/Dy
// halves (128 KB dynamic LDS) + bulk float4 writeback to P[b].
//
// Bottleneck model (fit to rounds 0/2/3): divergent-address ds_add_f32
// processes ~1 lane / ~4.4 cy / CU. 3.2M total atomics / 256 CUs ~= 23 us
// floor. Gather latency hides UNDER the atomic serialization (fused on
// purpose — round 4 showed splitting buys nothing and costs a dispatch).
// Contiguous net range per block: nps/fnp/net_weights reads coalesce
// (every net has 4 pins -> fnp int4 = contiguous 16 B/lane).
__global__ __launch_bounds__(TPB) void net_diff_kernel(
    const float* __restrict__ pin_pos,
    const float* __restrict__ net_weights,
    const int*   __restrict__ nps,
    const int*   __restrict__ fnp,
    float* __restrict__ P) {            // [B][NFL]
    extern __shared__ float Dl[];       // [Dx NCELL | Dy NCELL]
    const int tid = threadIdx.x;

    float4* D4 = (float4*)Dl;
    for (int i = tid; i < NFL / 4; i += TPB) D4[i] = make_float4(0, 0, 0, 0);
    __syncthreads();

    const int per = (NUM_NETS + gridDim.x - 1) / gridDim.x;   // 391
    const int n0  = blockIdx.x * per;
    const int n1  = min(n0 + per, NUM_NETS);

    for (int n = n0 + tid; n < n1; n += TPB) {
        int s = nps[n], e = nps[n + 1];
        if (e <= s) continue;
        float xmin, xmax, ymin, ymax;
        if (e - s == 4 && (s & 3) == 0) {
            int4 p4 = *(const int4*)(fnp + s);
            float x0 = pin_pos[p4.x], y0 = pin_pos[p4.x + NUM_PINS];
            float x1 = pin_pos[p4.y], y1 = pin_pos[p4.y + NUM_PINS];
            float x2 = pin_pos[p4.z], y2 = pin_pos[p4.z + NUM_PINS];
            float x3 = pin_pos[p4.w], y3 = pin_pos[p4.w + NUM_PINS];
            xmin = fminf(fminf(x0, x1), fminf(x2, x3));
            xmax = fmaxf(fmaxf(x0, x1), fmaxf(x2, x3));
            ymin = fminf(fminf(y0, y1), fminf(y2, y3));
            ymax = fmaxf(fmaxf(y0, y1), fmaxf(y2, y3));
        } else {
            xmin = 1e30f; xmax = -1e30f; ymin = 1e30f; ymax = -1e30f;
            for (int p = s; p < e; ++p) {
                int pin = fnp[p];
                float px = pin_pos[pin];
                float py = pin_pos[pin + NUM_PINS];
                xmin = fminf(xmin, px); xmax = fmaxf(xmax, px);
                ymin = fminf(ymin, py); ymax = fmaxf(ymax, py);
            }
        }
        float w  = net_weights[n];
        float dx = xmax - xmin, dy = ymax - ymin;
        float cx = (dy > 0.f) ? w / dy : 0.f;   // map_x coeff
        float cy = (dx > 0.f) ? w / dx : 0.f;   // map_y coeff
        if (cx == 0.f && cy == 0.f) continue;

        int ixs[4], iys[4];
        float vxs[4], vys[4];
        int nx = second_diff(xmin, xmax, ixs, vxs);
        int ny = second_diff(ymin, ymax, iys, vys);

        for (int i = 0; i < nx; ++i) {
            int row = ixs[i];
            float fi = vxs[i];
            if (fi == 0.f || row >= NB) continue;
            for (int j = 0; j < ny; ++j) {
                int col = iys[j];
                float t = fi * vys[j];
                if (t == 0.f || col >= NB) continue;
                int cell = row * NB + col;
                if (cx != 0.f) atomicAdd(&Dl[cell],         cx * t);
                if (cy != 0.f) atomicAdd(&Dl[NCELL + cell], cy * t);
            }
        }
    }
    __syncthreads();

    float4* Pb = (float4*)(P + (size_t)blockIdx.x * NFL);
    for (int i = tid; i < NFL / 4; i += TPB) Pb[i] = D4[i];
}

// K2: XCD-affine chunked reduce. Grid (NCHUNK=8, 32): chunk = blockIdx.x, so
// the linearized block id % 8 == chunk ~= this block's XCD; it sums slices
// b % 8 == chunk — the slices whose writer blocks (b % 8 == same XCD,
// heuristically) left them in THIS XCD's L2 (32 slices x 128 KB = 4 MB =
// exactly one XCD L2). Perf heuristic only; correctness is mapping-free.
__global__ __launch_bounds__(256) void reduce_kernel(
    const float4* __restrict__ P,   // [B][NFL/4]
    float4* __restrict__ Rc,        // [NCHUNK][NFL/4]
    int B) {
    constexpr int NF4 = NFL / 4;    // 8192
    int g = blockIdx.y * blockDim.x + threadIdx.x;   // 0..8191
    int chunk = blockIdx.x;                          // 0..7
    float4 a0 = {0,0,0,0}, a1 = {0,0,0,0}, a2 = {0,0,0,0}, a3 = {0,0,0,0};
    int b = chunk;
    for (; b + 3 * NCHUNK < B; b += 4 * NCHUNK) {
        float4 v0 = P[(size_t)(b             ) * NF4 + g];
        float4 v1 = P[(size_t)(b +     NCHUNK) * NF4 + g];
        float4 v2 = P[(size_t)(b + 2 * NCHUNK) * NF4 + g];
        float4 v3 = P[(size_t)(b + 3 * NCHUNK) * NF4 + g];
        a0.x += v0.x; a0.y += v0.y; a0.z += v0.z; a0.w += v0.w;
        a1.x += v1.x; a1.y += v1.y; a1.z += v1.z; a1.w += v1.w;
        a2.x += v2.x; a2.y += v2.y; a2.z += v2.z; a2.w += v2.w;
        a3.x += v3.x; a3.y += v3.y; a3.z += v3.z; a3.w += v3.w;
    }
    for (; b < B; b += NCHUNK) {
        float4 v = P[(size_t)b * NF4 + g];
        a0.x += v.x; a0.y += v.y; a0.z += v.z; a0.w += v.w;
    }
    float4 r;
    r.x = (a0.x + a1.x) + (a2.x + a3.x);
    r.y = (a0.y + a1.y) + (a2.y + a3.y);
    r.z = (a0.z + a1.z) + (a2.z + a3.z);
    r.w = (a0.w + a1.w) + (a2.w + a3.w);
    Rc[(size_t)chunk * NF4 + g] = r;
}

// K3: x-prefix. One block per y-column; thread t = x-row. Sums the 8 chunk
// maps for both (de-interleaved) halves, LDS Hillis-Steele scan over 128 rows.
__global__ __launch_bounds__(NB) void scan_x_kernel(
    const float* __restrict__ Rc,    // [NCHUNK][2][NCELL]
    float2* __restrict__ Xp) {       // [NCELL] float2, x-prefixed
    __shared__ float2 sm[NB];
    int col = blockIdx.x;
    int t = threadIdx.x;
    int idx = t * NB + col;
    float2 v = make_float2(0.f, 0.f);
    #pragma unroll
    for (int c = 0; c < NCHUNK; ++c) {
        v.x += Rc[(size_t)c * NFL + idx];
        v.y += Rc[(size_t)c * NFL + NCELL + idx];
    }
    sm[t] = v;
    __syncthreads();
    #pragma unroll
    for (int off = 1; off < NB; off <<= 1) {
        float2 cur = sm[t];
        float2 add = (t >= off) ? sm[t - off] : make_float2(0.f, 0.f);
        __syncthreads();
        cur.x += add.x; cur.y += add.y;
        sm[t] = cur;
        __syncthreads();
    }
    Xp[idx] = sm[t];
}

// K4: y-prefix + clip -> util. One block per x-row; coalesced float2 loads.
__global__ __launch_bounds__(NB) void scan_y_kernel(
    const float2* __restrict__ Xp,   // [NCELL] float2
    float* __restrict__ util) {
    __shared__ float2 sm[NB];
    int row = blockIdx.x;
    int t = threadIdx.x;
    sm[t] = Xp[row * NB + t];
    __syncthreads();
    #pragma unroll
    for (int off = 1; off < NB; off <<= 1) {
        float2 cur = sm[t];
        float2 add = (t >= off) ? sm[t - off] : make_float2(0.f, 0.f);
        __syncthreads();
        cur.x += add.x; cur.y += add.y;
        sm[t] = cur;
        __syncthreads();
    }
    constexpr float invx = 1.f / (S * S * UNIT_H_CAP);
    constexpr float invy = 1.f / (S * S * UNIT_V_CAP);
    float2 r = sm[t];
    float u = fmaxf(r.x * invx, r.y * invy);
    util[row * NB + t] = fminf(fmaxf(u, 0.5f), 2.0f);
}

// K5: per-movable-node area = sum over <=3x3 bins of ox*util*oy
__global__ __launch_bounds__(256) void node_kernel(
    const float* __restrict__ pos,
    const float* __restrict__ nsx,
    const float* __restrict__ nsy,
    const float* __restrict__ util,
    float* __restrict__ out) {
    int m = blockIdx.x * blockDim.x + threadIdx.x;
    if (m >= NUM_MOVABLE) return;
    float x  = pos[m];
    float y  = pos[NUM_NODES + m];
    float xh = x + nsx[m];
    float yh = y + nsy[m];
    int ax = max(0,      (int)floorf(x  / S) - 1);
    int bx = min(NB - 1, (int)floorf(xh / S) + 1);
    int ay = max(0,      (int)floorf(y  / S) - 1);
    int by = min(NB - 1, (int)floorf(yh / S) + 1);
    float acc = 0.f;
    for (int i = ax; i <= bx; ++i) {
        float ov = fminf(edgef(i + 1), xh) - fmaxf(edgef(i), x);
        if (ov <= 0.f) continue;
        float inner = 0.f;
        for (int j = ay; j <= by; ++j) {
            float ovy = fminf(edgef(j + 1), yh) - fmaxf(edgef(j), y);
            if (ovy > 0.f) inner += ovy * util[i * NB + j];
        }
        acc += ov * inner;
    }
    out[m] = acc;
}

extern "C" void kernel_launch(void* const* d_in, const int* in_sizes, int n_in,
                              void* d_out, int out_size, void* d_ws, size_t ws_size,
                              hipStream_t stream) {
    const float* pos      = (const float*)d_in[0];
    const float* pin_pos  = (const float*)d_in[1];
    const float* nsx      = (const float*)d_in[2];
    const float* nsy      = (const float*)d_in[3];
    const float* nw       = (const float*)d_in[4];
    const int*   npstart  = (const int*)d_in[5];
    const int*   fnp      = (const int*)d_in[6];
    float*       out      = (float*)d_out;

    // ws layout (floats): Rc[NCHUNK*NFL] | Xp[NFL] | util[NCELL] | P[B*NFL]
    float* w    = (float*)d_ws;
    float* Rc   = w;                           w += NCHUNK * NFL;
    float* Xp   = w;                           w += NFL;
    float* util = w;                           w += NCELL;
    float* P    = w;

    size_t fixed = (size_t)(w - (float*)d_ws) * sizeof(float);
    int B = NDB;
    if (ws_size > fixed) {
        size_t fit = (ws_size - fixed) / ((size_t)NFL * sizeof(float));
        if ((size_t)B > fit) B = (int)fit;
    } else {
        B = 1;
    }
    if (B < 1) B = 1;

    (void)hipFuncSetAttribute((const void*)net_diff_kernel,
                              hipFuncAttributeMaxDynamicSharedMemorySize,
                              NFL * (int)sizeof(float));

    net_diff_kernel<<<B, TPB, NFL * sizeof(float), stream>>>(
        pin_pos, nw, npstart, fnp, P);
    {
        dim3 g(NCHUNK, NFL / 4 / 256);   // (8, 32): blockIdx.x == chunk == XCD
        reduce_kernel<<<g, 256, 0, stream>>>(
            (const float4*)P, (float4*)Rc, B);
    }
    scan_x_kernel<<<NB, NB, 0, stream>>>(Rc, (float2*)Xp);
    scan_y_kernel<<<NB, NB, 0, stream>>>((const float2*)Xp, util);
    node_kernel<<<(NUM_MOVABLE + 255) / 256, 256, 0, stream>>>(
        pos, nsx, nsy, util, out);
}

// Round 6
// 114.986 us; speedup vs baseline: 1.1818x; 1.0104x over previous
//
#include <hip/hip_runtime.h>

// Problem constants (from reference)
constexpr int   NB         = 128;          // bins per axis
constexpr int   NCELL      = NB * NB;      // 16384 cells
constexpr int   NFL        = 2 * NCELL;    // [Dx | Dy] floats = 32768 (de-interleaved)
constexpr float S          = 7.8125f;      // 1000/128, exact in fp32
constexpr int   NUM_NETS   = 100000;
constexpr int   NUM_NODES  = 200000;
constexpr int   NUM_MOVABLE= 180000;
constexpr int   NUM_PINS   = 400000;
constexpr float UNIT_H_CAP = 1.5f;
constexpr float UNIT_V_CAP = 1.4f;

#define TPB    1024  // net_diff block size (16 waves)
#define NDB    256   // net_diff blocks: 1 per CU on ALL 256 CUs
#define NCHUNK 8     // reduce chunks == XCD count (XCD-affine slice sums)

__device__ __forceinline__ float edgef(int t) { return (float)t * S; }

__device__ __forceinline__ int bin_of(float v) {
    int t = (int)floorf(v / S);
    while (edgef(t + 1) <= v) ++t;
    while (edgef(t)     >  v) --t;
    return t;
}

__device__ __forceinline__ float phi(int t, float lo, float hi) {
    return fminf(fmaxf(edgef(t), lo), hi);
}

// K1: fused PIN-PARALLEL bbox gather + LDS-private scatter into
// DE-INTERLEAVED Dx/Dy halves (128 KB dynamic LDS) + bulk float4 writeback.
//
// Round-5 decomposition: net_diff ~35us = gather ~25 (latency-bound, only
// 6/16 waves active under one-net-per-thread) + LDS atomics ~10 + flush ~2.
// Fix: one net per 4-LANE GROUP. Lane l loads fnp[s+l] (fully coalesced
// across the wave) + 2 scattered pin loads; bbox = 2x shfl_xor within the
// group. ALL 16 waves now issue gather loads (2/thread, no 8-deep chain).
// The <=4x4 cell outer product is distributed: lane l owns x-entry l
// (computed scalar per lane — no runtime-indexed arrays -> no scratch).
__global__ __launch_bounds__(TPB) void net_diff_kernel(
    const float* __restrict__ pin_pos,
    const float* __restrict__ net_weights,
    const int*   __restrict__ nps,
    const int*   __restrict__ fnp,
    float* __restrict__ P) {            // [B][NFL]
    extern __shared__ float Dl[];       // [Dx NCELL | Dy NCELL]
    const int tid = threadIdx.x;

    float4* D4 = (float4*)Dl;
    for (int i = tid; i < NFL / 4; i += TPB) D4[i] = make_float4(0, 0, 0, 0);
    __syncthreads();

    const int per = (NUM_NETS + gridDim.x - 1) / gridDim.x;   // 391
    const int n0  = blockIdx.x * per;
    const int n1  = min(n0 + per, NUM_NETS);
    const int l   = tid & 3;       // lane within 4-lane group (pin index)
    const int g   = tid >> 2;      // group id within block
    constexpr int GP = TPB / 4;    // 256 nets per iteration

    for (int n = n0 + g; n < n1; n += GP) {
        // group-uniform trip count: all 4 lanes of a group reach the shfls
        int s = nps[n], e = nps[n + 1];
        bool ok = (e > s);
        float xmin, xmax, ymin, ymax;
        if (ok && (e - s == 4)) {
            int pin = fnp[s + l];          // coalesced: wave = 64 consecutive
            float xv = pin_pos[pin];
            float yv = pin_pos[pin + NUM_PINS];
            xmin = xv; xmax = xv; ymin = yv; ymax = yv;
        } else {
            xmin = 1e30f; xmax = -1e30f; ymin = 1e30f; ymax = -1e30f;
            if (ok && l == 0) {            // rare/never: serial fallback
                for (int p = s; p < e; ++p) {
                    int pin = fnp[p];
                    float px = pin_pos[pin];
                    float py = pin_pos[pin + NUM_PINS];
                    xmin = fminf(xmin, px); xmax = fmaxf(xmax, px);
                    ymin = fminf(ymin, py); ymax = fmaxf(ymax, py);
                }
            }
        }
        // 4-lane group min/max reduce (xor 1, xor 2 stay inside the group)
        xmin = fminf(xmin, __shfl_xor(xmin, 1));
        xmin = fminf(xmin, __shfl_xor(xmin, 2));
        xmax = fmaxf(xmax, __shfl_xor(xmax, 1));
        xmax = fmaxf(xmax, __shfl_xor(xmax, 2));
        ymin = fminf(ymin, __shfl_xor(ymin, 1));
        ymin = fminf(ymin, __shfl_xor(ymin, 2));
        ymax = fmaxf(ymax, __shfl_xor(ymax, 1));
        ymax = fmaxf(ymax, __shfl_xor(ymax, 2));
        if (!ok) continue;

        float w  = net_weights[n];
        float dx = xmax - xmin, dy = ymax - ymin;
        float cx = (dy > 0.f) ? w / dy : 0.f;   // map_x coeff
        float cy = (dx > 0.f) ? w / dx : 0.f;   // map_y coeff
        if (cx == 0.f && cy == 0.f) continue;

        // this lane's x-entry of the second difference (<=4 nonzeros)
        int ax = bin_of(xmin), bx = bin_of(xmax);
        int row; bool has;
        if      (l == 0) { row = ax;     has = true; }
        else if (l == 1) { row = ax + 1; has = true; }
        else if (l == 2) { row = bx;     has = (bx > ax + 1); }
        else             { row = bx + 1; has = (bx > ax); }
        if (!has || row >= NB) continue;
        float fi = phi(row + 1, xmin, xmax) - 2.f * phi(row, xmin, xmax)
                 + phi(row - 1, xmin, xmax);
        if (fi == 0.f) continue;

        int ay = bin_of(ymin), by = bin_of(ymax);
        #pragma unroll
        for (int j = 0; j < 4; ++j) {      // compile-time j: stays in regs
            int col; bool hj;
            if      (j == 0) { col = ay;     hj = true; }
            else if (j == 1) { col = ay + 1; hj = true; }
            else if (j == 2) { col = by;     hj = (by > ay + 1); }
            else             { col = by + 1; hj = (by > ay); }
            if (!hj || col >= NB) continue;
            float fj = phi(col + 1, ymin, ymax) - 2.f * phi(col, ymin, ymax)
                     + phi(col - 1, ymin, ymax);
            float t = fi * fj;
            if (t == 0.f) continue;
            int cell = row * NB + col;
            if (cx != 0.f) atomicAdd(&Dl[cell],         cx * t);
            if (cy != 0.f) atomicAdd(&Dl[NCELL + cell], cy * t);
        }
    }
    __syncthreads();

    float4* Pb = (float4*)(P + (size_t)blockIdx.x * NFL);
    for (int i = tid; i < NFL / 4; i += TPB) Pb[i] = D4[i];
}

// K2: XCD-affine chunked reduce. Grid (NCHUNK=8, 32): chunk = blockIdx.x ->
// linearized block id % 8 == chunk ~= this block's XCD; sums slices
// b % 8 == chunk (heuristically the slices resident in THIS XCD's L2).
__global__ __launch_bounds__(256) void reduce_kernel(
    const float4* __restrict__ P,   // [B][NFL/4]
    float4* __restrict__ Rc,        // [NCHUNK][NFL/4]
    int B) {
    constexpr int NF4 = NFL / 4;    // 8192
    int g = blockIdx.y * blockDim.x + threadIdx.x;   // 0..8191
    int chunk = blockIdx.x;                          // 0..7
    float4 a0 = {0,0,0,0}, a1 = {0,0,0,0}, a2 = {0,0,0,0}, a3 = {0,0,0,0};
    int b = chunk;
    for (; b + 3 * NCHUNK < B; b += 4 * NCHUNK) {
        float4 v0 = P[(size_t)(b             ) * NF4 + g];
        float4 v1 = P[(size_t)(b +     NCHUNK) * NF4 + g];
        float4 v2 = P[(size_t)(b + 2 * NCHUNK) * NF4 + g];
        float4 v3 = P[(size_t)(b + 3 * NCHUNK) * NF4 + g];
        a0.x += v0.x; a0.y += v0.y; a0.z += v0.z; a0.w += v0.w;
        a1.x += v1.x; a1.y += v1.y; a1.z += v1.z; a1.w += v1.w;
        a2.x += v2.x; a2.y += v2.y; a2.z += v2.z; a2.w += v2.w;
        a3.x += v3.x; a3.y += v3.y; a3.z += v3.z; a3.w += v3.w;
    }
    for (; b < B; b += NCHUNK) {
        float4 v = P[(size_t)b * NF4 + g];
        a0.x += v.x; a0.y += v.y; a0.z += v.z; a0.w += v.w;
    }
    float4 r;
    r.x = (a0.x + a1.x) + (a2.x + a3.x);
    r.y = (a0.y + a1.y) + (a2.y + a3.y);
    r.z = (a0.z + a1.z) + (a2.z + a3.z);
    r.w = (a0.w + a1.w) + (a2.w + a3.w);
    Rc[(size_t)chunk * NF4 + g] = r;
}

// K3: x-prefix. One block per y-column; thread t = x-row. Sums the 8 chunk
// maps for both (de-interleaved) halves, LDS Hillis-Steele scan over 128 rows.
__global__ __launch_bounds__(NB) void scan_x_kernel(
    const float* __restrict__ Rc,    // [NCHUNK][2][NCELL]
    float2* __restrict__ Xp) {       // [NCELL] float2, x-prefixed
    __shared__ float2 sm[NB];
    int col = blockIdx.x;
    int t = threadIdx.x;
    int idx = t * NB + col;
    float2 v = make_float2(0.f, 0.f);
    #pragma unroll
    for (int c = 0; c < NCHUNK; ++c) {
        v.x += Rc[(size_t)c * NFL + idx];
        v.y += Rc[(size_t)c * NFL + NCELL + idx];
    }
    sm[t] = v;
    __syncthreads();
    #pragma unroll
    for (int off = 1; off < NB; off <<= 1) {
        float2 cur = sm[t];
        float2 add = (t >= off) ? sm[t - off] : make_float2(0.f, 0.f);
        __syncthreads();
        cur.x += add.x; cur.y += add.y;
        sm[t] = cur;
        __syncthreads();
    }
    Xp[idx] = sm[t];
}

// K4: y-prefix + clip -> util. One block per x-row; coalesced float2 loads.
__global__ __launch_bounds__(NB) void scan_y_kernel(
    const float2* __restrict__ Xp,   // [NCELL] float2
    float* __restrict__ util) {
    __shared__ float2 sm[NB];
    int row = blockIdx.x;
    int t = threadIdx.x;
    sm[t] = Xp[row * NB + t];
    __syncthreads();
    #pragma unroll
    for (int off = 1; off < NB; off <<= 1) {
        float2 cur = sm[t];
        float2 add = (t >= off) ? sm[t - off] : make_float2(0.f, 0.f);
        __syncthreads();
        cur.x += add.x; cur.y += add.y;
        sm[t] = cur;
        __syncthreads();
    }
    constexpr float invx = 1.f / (S * S * UNIT_H_CAP);
    constexpr float invy = 1.f / (S * S * UNIT_V_CAP);
    float2 r = sm[t];
    float u = fmaxf(r.x * invx, r.y * invy);
    util[row * NB + t] = fminf(fmaxf(u, 0.5f), 2.0f);
}

// K5: per-movable-node area = sum over <=3x3 bins of ox*util*oy
__global__ __launch_bounds__(256) void node_kernel(
    const float* __restrict__ pos,
    const float* __restrict__ nsx,
    const float* __restrict__ nsy,
    const float* __restrict__ util,
    float* __restrict__ out) {
    int m = blockIdx.x * blockDim.x + threadIdx.x;
    if (m >= NUM_MOVABLE) return;
    float x  = pos[m];
    float y  = pos[NUM_NODES + m];
    float xh = x + nsx[m];
    float yh = y + nsy[m];
    int ax = max(0,      (int)floorf(x  / S) - 1);
    int bx = min(NB - 1, (int)floorf(xh / S) + 1);
    int ay = max(0,      (int)floorf(y  / S) - 1);
    int by = min(NB - 1, (int)floorf(yh / S) + 1);
    float acc = 0.f;
    for (int i = ax; i <= bx; ++i) {
        float ov = fminf(edgef(i + 1), xh) - fmaxf(edgef(i), x);
        if (ov <= 0.f) continue;
        float inner = 0.f;
        for (int j = ay; j <= by; ++j) {
            float ovy = fminf(edgef(j + 1), yh) - fmaxf(edgef(j), y);
            if (ovy > 0.f) inner += ovy * util[i * NB + j];
        }
        acc += ov * inner;
    }
    out[m] = acc;
}

extern "C" void kernel_launch(void* const* d_in, const int* in_sizes, int n_in,
                              void* d_out, int out_size, void* d_ws, size_t ws_size,
                              hipStream_t stream) {
    const float* pos      = (const float*)d_in[0];
    const float* pin_pos  = (const float*)d_in[1];
    const float* nsx      = (const float*)d_in[2];
    const float* nsy      = (const float*)d_in[3];
    const float* nw       = (const float*)d_in[4];
    const int*   npstart  = (const int*)d_in[5];
    const int*   fnp      = (const int*)d_in[6];
    float*       out      = (float*)d_out;

    // ws layout (floats): Rc[NCHUNK*NFL] | Xp[NFL] | util[NCELL] | P[B*NFL]
    float* w    = (float*)d_ws;
    float* Rc   = w;                           w += NCHUNK * NFL;
    float* Xp   = w;                           w += NFL;
    float* util = w;                           w += NCELL;
    float* P    = w;

    size_t fixed = (size_t)(w - (float*)d_ws) * sizeof(float);
    int B = NDB;
    if (ws_size > fixed) {
        size_t fit = (ws_size - fixed) / ((size_t)NFL * sizeof(float));
        if ((size_t)B > fit) B = (int)fit;
    } else {
        B = 1;
    }
    if (B < 1) B = 1;

    (void)hipFuncSetAttribute((const void*)net_diff_kernel,
                              hipFuncAttributeMaxDynamicSharedMemorySize,
                              NFL * (int)sizeof(float));

    net_diff_kernel<<<B, TPB, NFL * sizeof(float), stream>>>(
        pin_pos, nw, npstart, fnp, P);
    {
        dim3 g(NCHUNK, NFL / 4 / 256);   // (8, 32): blockIdx.x == chunk == XCD
        reduce_kernel<<<g, 256, 0, stream>>>(
            (const float4*)P, (float4*)Rc, B);
    }
    scan_x_kernel<<<NB, NB, 0, stream>>>(Rc, (float2*)Xp);
    scan_y_kernel<<<NB, NB, 0, stream>>>((const float2*)Xp, util);
    node_kernel<<<(NUM_MOVABLE + 255) / 256, 256, 0, stream>>>(
        pos, nsx, nsy, util, out);
}